// Round 15
// baseline (824.216 us; speedup 1.0000x reference)
//
#include <hip/hip_runtime.h>

#define T_OBS 8
#define PRED  12
#define NSTEP 20

typedef __attribute__((ext_vector_type(8))) short bf16x8;
typedef __attribute__((ext_vector_type(4))) float f32x4;
typedef __attribute__((ext_vector_type(2))) unsigned long long u64x2;
#define MFMA16(a,b,c) __builtin_amdgcn_mfma_f32_16x16x32_bf16((a),(b),(c),0,0,0)
#define AS __ATOMIC_RELAXED, __HIP_MEMORY_SCOPE_AGENT

// workspace offsets (bytes)
#define WP_OFF    0            // 128*8192*2 = 2097152
#define WZ_OFF    2097152      // 512*320*2  = 327680
#define BZ_OFF    2424832      // 2048
#define MASK_OFF  2426880      // 2048
#define CUR_OFF   2428928      // 4096
#define HG0_OFF   2433024      // 131072
#define HG1_OFF   2564096      // 131072
#define CST_OFF   2695168      // 262144
#define XIN_OFF   2957312      // 196608
#define U_OFF     3153920      // 8388608
#define LSTP_OFF  11542528     // 4718592
#define NVP_OFF   16261120     // 18432
#define BAR_OFF   16279552     // 8192 -> ends ~16.29 MB

// coherent cross-XCD helpers: relaxed agent atomics (write-through / uncached)
static __device__ __forceinline__ void st32c(void* p, unsigned v){
    __hip_atomic_store((unsigned*)p, v, AS);
}
static __device__ __forceinline__ unsigned ld32c(const void* p){
    return __hip_atomic_load((const unsigned*)p, AS);
}
static __device__ __forceinline__ unsigned long long ld64c(const void* p){
    return __hip_atomic_load((const unsigned long long*)p, AS);
}
static __device__ __forceinline__ bf16x8 ldfragc(const unsigned short* p){
    union { unsigned long long q[2]; bf16x8 v; } u;
    u.q[0] = ld64c(p); u.q[1] = ld64c(p + 4);
    return u.v;
}

static __device__ __forceinline__ unsigned short f2bf(float x){
    union { float f; unsigned u; } v; v.f = x;
    unsigned r = v.u + 0x7fffu + ((v.u >> 16) & 1u);   // RNE
    return (unsigned short)(r >> 16);
}
static __device__ __forceinline__ unsigned pack2(float a, float b){
    return (unsigned)f2bf(a) | ((unsigned)f2bf(b) << 16);
}
static __device__ __forceinline__ float bf2lo(unsigned v){ return __uint_as_float(v << 16); }
static __device__ __forceinline__ float bf2hi(unsigned v){ return __uint_as_float(v & 0xffff0000u); }
static __device__ __forceinline__ float sigm_f(float x){ return 1.f / (1.f + __expf(-x)); }
static __device__ __forceinline__ float tanh_f(float x){
    float e = __expf(-2.f * fabsf(x));
    float t = (1.f - e) / (1.f + e);
    return copysignf(t, x);
}

// fence-free two-level grid barrier (relaxed monotonic counters; & masks make
// it tolerant of accumulated counts across dispatches; prep re-zeroes bar).
static __device__ __forceinline__ void gridbar(int* bar, int bid, int target){
    __syncthreads();   // compiler drains vmcnt per wave before s_barrier
    if (threadIdx.x == 0){
        int p = __hip_atomic_fetch_add(&bar[32 + (bid >> 3)*16], 1, AS);
        if ((p & 7) == 7){
            int q = __hip_atomic_fetch_add(&bar[16], 1, AS);
            if ((q & 63) == 63)
                __hip_atomic_store(&bar[0], target, AS);
        }
        int spins = 0;
        while (__hip_atomic_load(&bar[0], AS) < target){
            __builtin_amdgcn_s_sleep(1);
            if (++spins > (1 << 22)) break;   // fail loud, never hang
        }
        asm volatile("" ::: "memory");
    }
    __syncthreads();
}

// ---------------- prep: weights->bf16, state init, encoder lists, bar=0 -------
__global__ __launch_bounds__(256) void prep(
    const float* __restrict__ obs, const float* __restrict__ Wp,
    const float* __restrict__ Wih, const float* __restrict__ Whh,
    const float* __restrict__ bih, const float* __restrict__ bhh,
    const unsigned char* __restrict__ mraw,
    unsigned short* __restrict__ wp_bf, unsigned short* __restrict__ wz,
    float* __restrict__ bz, int* __restrict__ mski,
    unsigned* __restrict__ hg1, float* __restrict__ cst,
    short* __restrict__ lst_pre, int* __restrict__ nv_pre,
    int* __restrict__ bar)
{
    __shared__ int maskl[512];
    __shared__ float2 posl[512];
    __shared__ short  celll[512];
    __shared__ int mflagA, mflagB;
    const int bid = blockIdx.x, tid = threadIdx.x;
    const int i0 = bid * 256 + tid, stride = 512 * 256;

    if (tid == 0){ mflagA = 0; mflagB = 0; }
    __syncthreads();
    for (int j = tid; j < 512; j += 256){
        unsigned char b = mraw[j];
        if (b && (j & 3))        atomicAdd(&mflagA, 1);
        if (b && ((j & 7) == 4)) atomicAdd(&mflagB, 1);
    }
    __syncthreads();
    for (int j = tid; j < 512; j += 256){
        int v;
        if (mflagA)      v = mraw[j] ? 1 : 0;
        else if (mflagB) v = ((const int*)mraw)[j] ? 1 : 0;
        else             v = ((const long long*)mraw)[j] ? 1 : 0;
        maskl[j] = v;
        if (bid == 0) mski[j] = v;
    }
    __syncthreads();

    for (int i = i0; i < 524288; i += stride)
        ((unsigned*)wp_bf)[i] = pack2(Wp[2*i], Wp[2*i + 1]);
    for (int i = i0; i < 81920; i += stride){
        int n = (2*i) / 320, k = (2*i) - n*320;
        float w0 = (k < 192)     ? Wih[n*192 + k]     : Whh[n*128 + k - 192];
        float w1 = (k + 1 < 192) ? Wih[n*192 + k + 1] : Whh[n*128 + k + 1 - 192];
        ((unsigned*)wz)[i] = pack2(w0, w1);
    }
    for (int i = i0; i < 512; i += stride) bz[i] = bih[i] + bhh[i];
    for (int i = i0; i < 32768; i += stride) hg1[i] = 0u;      // h(-1) = 0
    for (int i = i0; i < 65536; i += stride) cst[i] = 0.f;     // c(-1) = 0
    for (int i = i0; i < 2048; i += stride) bar[i] = 0;        // barrier reset

    // encoder-step neighbor lists: t = 0..8 (t==8 uses obs[7], mask-zeroed)
    const int vi = maskl[bid];
    for (int tt = 0; tt <= 8; ++tt){
        const int to = (tt < 8) ? tt : 7;
        __syncthreads();
        for (int j = tid; j < 512; j += 256){
            float px = obs[to*1024 + 2*j], py = obs[to*1024 + 2*j + 1];
            if (isnan(px)) px = 0.f;
            if (isnan(py)) py = 0.f;
            if (tt == 8 && !maskl[j]){ px = 0.f; py = 0.f; }
            posl[j] = make_float2(px, py);
        }
        __syncthreads();
        const float2 pi = posl[bid];
        for (int j = tid; j < 512; j += 256){
            int cc = -1;
            if (vi && j != bid && maskl[j]){
                float rx = posl[j].x - pi.x, ry = posl[j].y - pi.y;
                if (fabsf(rx) < 32.f && fabsf(ry) < 32.f){
                    int col = (int)floorf((rx + 32.f) * 0.125f);
                    int row = (int)floorf((ry + 32.f) * 0.125f);
                    col = min(max(col, 0), 7); row = min(max(row, 0), 7);
                    cc = row*8 + col;
                }
            }
            celll[j] = (short)cc;
        }
        __syncthreads();
        if (tid < 64){
            short* lp = lst_pre + ((long long)tt*512 + bid)*512;
            int base = 0;
            for (int b = 0; b < 8; ++b){
                short cj = celll[b*64 + tid];
                bool val = cj >= 0;
                unsigned long long bal = __ballot(val);
                int pre = __popcll(bal & ((1ull << tid) - 1ull));
                if (val) lp[base + pre] = (short)((b*64 + tid) | ((int)cj << 9));
                base += __popcll(bal);
            }
            if (tid == 0) nv_pre[tt*512 + bid] = base;
        }
    }
}

// LDS union for the three phases
union StepSmem {
    struct { float2 pos[512]; short cells[512]; short lst[512];
             float socp[8][128]; } a;                 // 10.2 KB
    struct { float zpart[2][4][16][16]; float hst[16][17]; } b;   // 9.3 KB
    struct { unsigned short ustage[32][256]; } c;     // 16 KB
};

// ---------------- STEP: one dispatch = one timestep (3 phases, 2 gridbars) ----
__global__ __launch_bounds__(256, 2) void step(
    const float* __restrict__ obs, const int* __restrict__ mski,
    const unsigned short* __restrict__ wp, const unsigned short* __restrict__ wz,
    const float* __restrict__ bz, const float* __restrict__ b_p,
    const float* __restrict__ W_e, const float* __restrict__ b_e,
    const float* __restrict__ W_o, const float* __restrict__ b_o,
    const short* __restrict__ lst_pre, const int* __restrict__ nv_pre,
    float* __restrict__ cur, const unsigned short* __restrict__ hg_rd,
    unsigned short* __restrict__ hg_wr, float* __restrict__ cst,
    unsigned short* __restrict__ xin, unsigned short* __restrict__ U,
    int* __restrict__ bar, float* __restrict__ out, int t)
{
    __shared__ StepSmem sm;
    __shared__ int nvS;
    const int bid = blockIdx.x, tid = threadIdx.x;
    const int w = tid >> 6, lane = tid & 63;
    const int lrow = lane & 15, lk = (lane >> 4) * 8;
    const int crow = (lane >> 4) * 4, ccol = lane & 15;

    // ================= PHASE A: gather U(t) + soc/emb -> xin (atomics) =======
    {
        float2 pi;
        int n;
        const int vi = mski[bid];
        if (t <= 8){
            const int to = (t < 8) ? t : 7;
            float px = obs[to*1024 + 2*bid], py = obs[to*1024 + 2*bid + 1];
            if (isnan(px)) px = 0.f;
            if (isnan(py)) py = 0.f;
            if (t == 8 && !vi){ px = 0.f; py = 0.f; }
            pi = make_float2(px, py);
            const short* lp = lst_pre + ((long long)t*512 + bid)*512;
            for (int e = tid; e < 512; e += 256) sm.a.lst[e] = lp[e];
            n = (t == 0) ? 0 : nv_pre[t*512 + bid];
            __syncthreads();
        } else {
            for (int s = 0; s < 2; ++s){
                int j = tid + s*256;
                sm.a.pos[j] = ((const float2*)cur)[j];   // boundary-coherent
            }
            __syncthreads();
            pi = sm.a.pos[bid];
            for (int s = 0; s < 2; ++s){
                int j = tid + s*256;
                int cc = -1;
                if (vi && j != bid && mski[j]){
                    float rx = sm.a.pos[j].x - pi.x, ry = sm.a.pos[j].y - pi.y;
                    if (fabsf(rx) < 32.f && fabsf(ry) < 32.f){
                        int col = (int)floorf((rx + 32.f) * 0.125f);
                        int row = (int)floorf((ry + 32.f) * 0.125f);
                        col = min(max(col, 0), 7); row = min(max(row, 0), 7);
                        cc = row*8 + col;
                    }
                }
                sm.a.cells[j] = (short)cc;
            }
            __syncthreads();
            if (tid < 64){
                int base = 0;
                for (int b = 0; b < 8; ++b){
                    short cj = sm.a.cells[b*64 + tid];
                    bool val = cj >= 0;
                    unsigned long long bal = __ballot(val);
                    int pre = __popcll(bal & ((1ull << tid) - 1ull));
                    if (val) sm.a.lst[base + pre] = (short)((b*64 + tid) | ((int)cj << 9));
                    base += __popcll(bal);
                }
                if (tid == 0) nvS = base;
            }
            __syncthreads();
            n = nvS;
        }
        // gather: 8 slots x unroll 16 -> 128 rows in flight (NT cached loads)
        {
            const int slot = tid >> 5, lq = tid & 31;
            const unsigned long long* ub = (const unsigned long long*)U;
            float s0 = 0.f, s1 = 0.f, s2 = 0.f, s3 = 0.f;
            int b4 = 0;
            for (; b4 + 128 <= n; b4 += 128){
                unsigned long long v[16];
                #pragma unroll
                for (int u = 0; u < 16; ++u){
                    int pk = sm.a.lst[b4 + u*8 + slot];
                    v[u] = __builtin_nontemporal_load(
                               ub + (pk & 511)*2048 + (pk >> 9)*32 + lq);
                }
                #pragma unroll
                for (int u = 0; u < 16; ++u){
                    unsigned lo = (unsigned)v[u], hi = (unsigned)(v[u] >> 32);
                    s0 += bf2lo(lo); s1 += bf2hi(lo);
                    s2 += bf2lo(hi); s3 += bf2hi(hi);
                }
            }
            for (; b4 + 32 <= n; b4 += 32){
                unsigned long long v[4];
                #pragma unroll
                for (int u = 0; u < 4; ++u){
                    int pk = sm.a.lst[b4 + u*8 + slot];
                    v[u] = __builtin_nontemporal_load(
                               ub + (pk & 511)*2048 + (pk >> 9)*32 + lq);
                }
                #pragma unroll
                for (int u = 0; u < 4; ++u){
                    unsigned lo = (unsigned)v[u], hi = (unsigned)(v[u] >> 32);
                    s0 += bf2lo(lo); s1 += bf2hi(lo);
                    s2 += bf2lo(hi); s3 += bf2hi(hi);
                }
            }
            for (; b4 + 8 <= n; b4 += 8){
                int pk = sm.a.lst[b4 + slot];
                unsigned long long v = __builtin_nontemporal_load(
                                           ub + (pk & 511)*2048 + (pk >> 9)*32 + lq);
                unsigned lo = (unsigned)v, hi = (unsigned)(v >> 32);
                s0 += bf2lo(lo); s1 += bf2hi(lo); s2 += bf2lo(hi); s3 += bf2hi(hi);
            }
            if (b4 + slot < n){
                int pk = sm.a.lst[b4 + slot];
                unsigned long long v = __builtin_nontemporal_load(
                                           ub + (pk & 511)*2048 + (pk >> 9)*32 + lq);
                unsigned lo = (unsigned)v, hi = (unsigned)(v >> 32);
                s0 += bf2lo(lo); s1 += bf2hi(lo); s2 += bf2lo(hi); s3 += bf2hi(hi);
            }
            f32x4 sv = {s0, s1, s2, s3};
            *(f32x4*)&sm.a.socp[slot][lq*4] = sv;
        }
        __syncthreads();
        unsigned* xin32 = (unsigned*)xin;
        if (tid < 64){
            float s0 = b_p[2*tid], s1 = b_p[2*tid + 1];
            #pragma unroll
            for (int p = 0; p < 8; ++p){
                s0 += sm.a.socp[p][2*tid];
                s1 += sm.a.socp[p][2*tid + 1];
            }
            if (!vi){ s0 = 0.f; s1 = 0.f; }
            st32c(xin32 + bid*96 + 32 + tid, pack2(s0, s1));
        } else if (tid < 96){
            int u = tid - 64;
            float e0 = fmaxf(W_e[(2*u    )*2]*pi.x + W_e[(2*u    )*2 + 1]*pi.y + b_e[2*u    ], 0.f);
            float e1 = fmaxf(W_e[(2*u + 1)*2]*pi.x + W_e[(2*u + 1)*2 + 1]*pi.y + b_e[2*u + 1], 0.f);
            st32c(xin32 + bid*96 + u, pack2(e0, e1));
        }
    }
    gridbar(bar, bid, 2*t + 1);

    // ================= PHASE B: LSTM (blocks 0-255 = rt x uo) ================
    if (bid < 256){
        const int rt = bid >> 3, uo = bid & 7;
        const int r0 = rt * 16, u0 = uo * 16;
        const int gh = w & 1, p = w >> 1;

        f32x4 acc[2] = {};
        #pragma unroll
        for (int kk = 0; kk < 5; ++kk){
            const int ks = p*5 + kk;
            const int row = r0 + lrow;
            bf16x8 a;
            if (ks < 6) a = ldfragc(xin + row*192 + ks*32 + lk);       // atomic
            else        a = *(const bf16x8*)(hg_rd + row*128 + (ks - 6)*32 + lk);
            #pragma unroll
            for (int gi = 0; gi < 2; ++gi){
                const int g = gh*2 + gi;
                bf16x8 b = *(const bf16x8*)(wz + (g*128 + u0 + lrow)*320 + ks*32 + lk);
                acc[gi] = MFMA16(a, b, acc[gi]);
            }
        }
        #pragma unroll
        for (int gi = 0; gi < 2; ++gi)
            #pragma unroll
            for (int r = 0; r < 4; ++r)
                sm.b.zpart[p][gh*2 + gi][crow + r][ccol] = acc[gi][r];
        __syncthreads();

        {
            int row = tid >> 4, lu = tid & 15;
            int unit = u0 + lu;
            float zi = sm.b.zpart[0][0][row][lu] + sm.b.zpart[1][0][row][lu] + bz[      unit];
            float zf = sm.b.zpart[0][1][row][lu] + sm.b.zpart[1][1][row][lu] + bz[128 + unit];
            float zg = sm.b.zpart[0][2][row][lu] + sm.b.zpart[1][2][row][lu] + bz[256 + unit];
            float zo = sm.b.zpart[0][3][row][lu] + sm.b.zpart[1][3][row][lu] + bz[384 + unit];
            float ig = sigm_f(zi), fg = sigm_f(zf);
            float gv = tanh_f(zg), og = sigm_f(zo);
            int gi2 = (r0 + row)*128 + unit;
            float cn = fg * cst[gi2] + ig * gv;     // block-private RW
            float hn = og * tanh_f(cn);
            cst[gi2] = cn;
            sm.b.hst[row][lu] = hn;
        }
        __syncthreads();
        if (tid < 128){
            int row = tid >> 3, pp = tid & 7;
            st32c((unsigned*)hg_wr + (r0 + row)*64 + uo*8 + pp,
                  pack2(sm.b.hst[row][2*pp], sm.b.hst[row][2*pp + 1]));
        }
    }
    gridbar(bar, bid, 2*t + 2);

    // ================= PHASE C: U(t+1) GEMM + decoder head ===================
    const int mq = bid >> 5, cp = bid & 31;
    const int r0c = mq * 32;
    if (t < NSTEP - 1){
        const int msub = w & 1, nq = w >> 1;
        bf16x8 afr[4];
        #pragma unroll
        for (int ks = 0; ks < 4; ++ks)
            afr[ks] = ldfragc(hg_wr + (r0c + msub*16 + lrow)*128 + ks*32 + lk);
        f32x4 acc[2][4] = {};
        #pragma unroll
        for (int ks = 0; ks < 4; ++ks){
            #pragma unroll
            for (int cell = 0; cell < 2; ++cell){
                #pragma unroll
                for (int ntl = 0; ntl < 4; ++ntl){
                    const unsigned short* bp = wp +
                        ((nq*4 + ntl)*16 + lrow)*8192 + (2*cp + cell)*128 + ks*32 + lk;
                    acc[cell][ntl] = MFMA16(afr[ks], *(const bf16x8*)bp, acc[cell][ntl]);
                }
            }
        }
        #pragma unroll
        for (int cell = 0; cell < 2; ++cell)
            #pragma unroll
            for (int ntl = 0; ntl < 4; ++ntl)
                #pragma unroll
                for (int r = 0; r < 4; ++r)
                    sm.c.ustage[msub*16 + crow + r][cell*128 + (nq*4 + ntl)*16 + ccol]
                        = f2bf(acc[cell][ntl][r]);
        __syncthreads();
        for (int e = tid; e < 1024; e += 256){
            int r = e >> 5, o = e & 31;
            u64x2 v = *(const u64x2*)&sm.c.ustage[r][o*8];
            __builtin_nontemporal_store(v,
                (u64x2*)((char*)U + ((long long)(r0c + r)*64 + 2*cp)*256 + o*16));
        }
    }
    if (t >= T_OBS && cp == 0){
        const int dec_t = t - T_OBS;
        for (int s = 0; s < 8; ++s){
            int ag = r0c + w*8 + s;
            unsigned hv = ld32c((const unsigned*)hg_wr + ag*64 + lane);
            float h0 = bf2lo(hv), h1 = bf2hi(hv);
            float pr[5];
            #pragma unroll
            for (int o = 0; o < 5; ++o)
                pr[o] = W_o[o*128 + 2*lane]*h0 + W_o[o*128 + 2*lane + 1]*h1;
            #pragma unroll
            for (int sh = 32; sh; sh >>= 1)
                #pragma unroll
                for (int o = 0; o < 5; ++o) pr[o] += __shfl_xor(pr[o], sh, 64);
            if (lane == 0){
                float mu0 = pr[0] + b_o[0], mu1 = pr[1] + b_o[1];
                float s0 = __expf(pr[2] + b_o[2]) + 1e-6f;
                float s1 = __expf(pr[3] + b_o[3]) + 1e-6f;
                float rh = tanh_f(pr[4] + b_o[4]);
                float cx, cy;
                if (dec_t == 0){
                    cx = obs[7*1024 + ag*2]; cy = obs[7*1024 + ag*2 + 1];
                    if (isnan(cx)) cx = 0.f;
                    if (isnan(cy)) cy = 0.f;
                    if (!mski[ag]){ cx = 0.f; cy = 0.f; }
                } else {
                    cx = cur[ag*2]; cy = cur[ag*2 + 1];   // boundary-coherent
                }
                if (mski[ag]){ cx += mu0; cy += mu1; }
                cur[ag*2] = cx; cur[ag*2 + 1] = cy;
                out[dec_t*1024 + ag*2]             = cx;
                out[dec_t*1024 + ag*2 + 1]         = cy;
                out[12288 + dec_t*1024 + ag*2]     = s0;
                out[12288 + dec_t*1024 + ag*2 + 1] = s1;
                out[24576 + dec_t*512 + ag]        = rh;
            }
        }
    }
}

extern "C" void kernel_launch(void* const* d_in, const int* in_sizes, int n_in,
                              void* d_out, int out_size, void* d_ws, size_t ws_size,
                              hipStream_t stream)
{
    const float* obs  = (const float*)d_in[0];
    const unsigned char* mraw = (const unsigned char*)d_in[1];
    const float* W_e  = (const float*)d_in[2];
    const float* b_e  = (const float*)d_in[3];
    const float* W_p  = (const float*)d_in[4];
    const float* b_p  = (const float*)d_in[5];
    const float* W_ih = (const float*)d_in[6];
    const float* W_hh = (const float*)d_in[7];
    const float* b_ih = (const float*)d_in[8];
    const float* b_hh = (const float*)d_in[9];
    const float* W_o  = (const float*)d_in[10];
    const float* b_o  = (const float*)d_in[11];
    float* out = (float*)d_out;

    char* ws = (char*)d_ws;
    unsigned short* wp_bf = (unsigned short*)(ws + WP_OFF);
    unsigned short* wz_bf = (unsigned short*)(ws + WZ_OFF);
    float* bz   = (float*)(ws + BZ_OFF);
    int*   mski = (int*)  (ws + MASK_OFF);
    float* cur  = (float*)(ws + CUR_OFF);
    unsigned short* hg[2] = { (unsigned short*)(ws + HG0_OFF),
                              (unsigned short*)(ws + HG1_OFF) };
    float* cst  = (float*)(ws + CST_OFF);
    unsigned short* xin = (unsigned short*)(ws + XIN_OFF);
    unsigned short* U   = (unsigned short*)(ws + U_OFF);
    short* lst_pre = (short*)(ws + LSTP_OFF);
    int*   nv_pre  = (int*)  (ws + NVP_OFF);
    int*   bar     = (int*)  (ws + BAR_OFF);

    prep<<<512, 256, 0, stream>>>(obs, W_p, W_ih, W_hh, b_ih, b_hh, mraw,
                                  wp_bf, wz_bf, bz, mski,
                                  (unsigned*)hg[1], cst, lst_pre, nv_pre, bar);

    for (int t = 0; t < NSTEP; ++t){
        step<<<512, 256, 0, stream>>>(obs, mski, wp_bf, wz_bf, bz, b_p,
                                      W_e, b_e, W_o, b_o, lst_pre, nv_pre,
                                      cur, hg[(t + 1) & 1], hg[t & 1],
                                      cst, xin, U, bar, out, t);
    }
}

// Round 16
// 529.983 us; speedup vs baseline: 1.5552x; 1.5552x over previous
//
#include <hip/hip_runtime.h>

#define T_OBS 8
#define PRED  12

typedef __attribute__((ext_vector_type(8))) short bf16x8;
typedef __attribute__((ext_vector_type(4))) float f32x4;
typedef __attribute__((ext_vector_type(2))) unsigned long long u64x2;
#define MFMA16(a,b,c) __builtin_amdgcn_mfma_f32_16x16x32_bf16((a),(b),(c),0,0,0)

// workspace offsets (bytes)
#define WP_OFF    0            // 128*8192*2 = 2097152
#define WZ_OFF    2097152      // 512*320*2  = 327680
#define BZ_OFF    2424832      // 2048
#define MASK_OFF  2426880      // 2048
#define CUR_OFF   2428928      // 4096
#define HG0_OFF   2433024      // 131072
#define CST_OFF   2564096      // 262144
#define XIN_OFF   2826240      // 196608
#define U_OFF     3022848      // 8388608
#define LSTP_OFF  11411456     // 4718592
#define NVP_OFF   16130048     // 18432
#define HG1_OFF   16148480     // 131072 -> ends ~16.28 MB

static __device__ __forceinline__ unsigned short f2bf(float x){
    union { float f; unsigned u; } v; v.f = x;
    unsigned r = v.u + 0x7fffu + ((v.u >> 16) & 1u);   // RNE
    return (unsigned short)(r >> 16);
}
static __device__ __forceinline__ unsigned pack2(float a, float b){
    return (unsigned)f2bf(a) | ((unsigned)f2bf(b) << 16);
}
static __device__ __forceinline__ float bf2lo(unsigned v){ return __uint_as_float(v << 16); }
static __device__ __forceinline__ float bf2hi(unsigned v){ return __uint_as_float(v & 0xffff0000u); }
static __device__ __forceinline__ float sigm_f(float x){ return 1.f / (1.f + __expf(-x)); }
static __device__ __forceinline__ float tanh_f(float x){
    float e = __expf(-2.f * fabsf(x));
    float t = (1.f - e) / (1.f + e);
    return copysignf(t, x);
}

// ---------------- prep: weights->bf16, state init, encoder lists, xin(0) ------
__global__ __launch_bounds__(256) void prep(
    const float* __restrict__ obs, const float* __restrict__ Wp,
    const float* __restrict__ Wih, const float* __restrict__ Whh,
    const float* __restrict__ bih, const float* __restrict__ bhh,
    const unsigned char* __restrict__ mraw,
    const float* __restrict__ W_e, const float* __restrict__ b_e,
    const float* __restrict__ b_p,
    unsigned short* __restrict__ wp_bf, unsigned short* __restrict__ wz,
    float* __restrict__ bz, int* __restrict__ mski,
    unsigned* __restrict__ hg1, float* __restrict__ cst,
    short* __restrict__ lst_pre, int* __restrict__ nv_pre,
    unsigned short* __restrict__ xin)
{
    __shared__ int maskl[512];
    __shared__ float2 posl[512];
    __shared__ short  celll[512];
    __shared__ int mflagA, mflagB;
    const int bid = blockIdx.x, tid = threadIdx.x;
    const int i0 = bid * 256 + tid, stride = 512 * 256;

    if (tid == 0){ mflagA = 0; mflagB = 0; }
    __syncthreads();
    for (int j = tid; j < 512; j += 256){
        unsigned char b = mraw[j];
        if (b && (j & 3))        atomicAdd(&mflagA, 1);
        if (b && ((j & 7) == 4)) atomicAdd(&mflagB, 1);
    }
    __syncthreads();
    for (int j = tid; j < 512; j += 256){
        int v;
        if (mflagA)      v = mraw[j] ? 1 : 0;
        else if (mflagB) v = ((const int*)mraw)[j] ? 1 : 0;
        else             v = ((const long long*)mraw)[j] ? 1 : 0;
        maskl[j] = v;
        if (bid == 0) mski[j] = v;
    }
    __syncthreads();

    for (int i = i0; i < 524288; i += stride)
        ((unsigned*)wp_bf)[i] = pack2(Wp[2*i], Wp[2*i + 1]);
    for (int i = i0; i < 81920; i += stride){
        int n = (2*i) / 320, k = (2*i) - n*320;
        float w0 = (k < 192)     ? Wih[n*192 + k]     : Whh[n*128 + k - 192];
        float w1 = (k + 1 < 192) ? Wih[n*192 + k + 1] : Whh[n*128 + k + 1 - 192];
        ((unsigned*)wz)[i] = pack2(w0, w1);
    }
    for (int i = i0; i < 512; i += stride) bz[i] = bih[i] + bhh[i];
    for (int i = i0; i < 32768; i += stride) hg1[i] = 0u;      // h(-1) = 0
    for (int i = i0; i < 65536; i += stride) cst[i] = 0.f;     // c(-1) = 0

    // encoder-step neighbor lists: t = 0..8 (t==8 uses obs[7], mask-zeroed)
    const int vi = maskl[bid];
    for (int tt = 0; tt <= 8; ++tt){
        const int to = (tt < 8) ? tt : 7;
        __syncthreads();
        for (int j = tid; j < 512; j += 256){
            float px = obs[to*1024 + 2*j], py = obs[to*1024 + 2*j + 1];
            if (isnan(px)) px = 0.f;
            if (isnan(py)) py = 0.f;
            if (tt == 8 && !maskl[j]){ px = 0.f; py = 0.f; }
            posl[j] = make_float2(px, py);
        }
        __syncthreads();
        const float2 pi = posl[bid];
        if (tt == 0){
            // xin(0): soc = masked b_p (gather of h=0 is empty), emb from obs[0]
            if (tid < 128){
                float s = b_p[tid];
                if (!vi) s = 0.f;
                xin[bid*192 + 64 + tid] = f2bf(s);
            } else if (tid < 192){
                int u = tid - 128;
                float e = W_e[u*2]*pi.x + W_e[u*2 + 1]*pi.y + b_e[u];
                xin[bid*192 + u] = f2bf(fmaxf(e, 0.f));
            }
        }
        for (int j = tid; j < 512; j += 256){
            int cc = -1;
            if (vi && j != bid && maskl[j]){
                float rx = posl[j].x - pi.x, ry = posl[j].y - pi.y;
                if (fabsf(rx) < 32.f && fabsf(ry) < 32.f){
                    int col = (int)floorf((rx + 32.f) * 0.125f);
                    int row = (int)floorf((ry + 32.f) * 0.125f);
                    col = min(max(col, 0), 7); row = min(max(row, 0), 7);
                    cc = row*8 + col;
                }
            }
            celll[j] = (short)cc;
        }
        __syncthreads();
        if (tid < 64){
            short* lp = lst_pre + ((long long)tt*512 + bid)*512;
            int base = 0;
            for (int b = 0; b < 8; ++b){
                short cj = celll[b*64 + tid];
                bool val = cj >= 0;
                unsigned long long bal = __ballot(val);
                int pre = __popcll(bal & ((1ull << tid) - 1ull));
                if (val) lp[base + pre] = (short)((b*64 + tid) | ((int)cj << 9));
                base += __popcll(bal);
            }
            if (tid == 0) nv_pre[tt*512 + bid] = base;
        }
    }
}

// ---------------- KU: head(t-1) + U-GEMM from compact hg ----------------------
// block (mq 0..15, cp 0..31): rows mq*32..+32, cells {2cp, 2cp+1}
__global__ __launch_bounds__(256) void ku(
    const unsigned short* __restrict__ hg,
    const unsigned short* __restrict__ wp_bf,
    const float* __restrict__ obs, const float* __restrict__ W_o,
    const float* __restrict__ b_o, const int* __restrict__ mski,
    float* __restrict__ cur, float* __restrict__ out,
    unsigned short* __restrict__ U, int t)
{
    __shared__ unsigned short ustage[32][256];   // 16 KB
    const int bid = blockIdx.x, tid = threadIdx.x;

    // ---- decoder head for step t-1 (agent = bid) ----
    if (t > T_OBS && tid < 64){
        const int dec_t = t - T_OBS - 1;                 // 0..11
        unsigned v = ((const unsigned*)hg)[bid*64 + tid];
        float h0 = bf2lo(v), h1 = bf2hi(v);
        float p[5];
        #pragma unroll
        for (int o = 0; o < 5; ++o)
            p[o] = W_o[o*128 + 2*tid]*h0 + W_o[o*128 + 2*tid + 1]*h1;
        #pragma unroll
        for (int s = 32; s; s >>= 1)
            #pragma unroll
            for (int o = 0; o < 5; ++o) p[o] += __shfl_xor(p[o], s, 64);
        if (tid == 0){
            float mu0 = p[0] + b_o[0], mu1 = p[1] + b_o[1];
            float s0 = __expf(p[2] + b_o[2]) + 1e-6f;
            float s1 = __expf(p[3] + b_o[3]) + 1e-6f;
            float rh = tanh_f(p[4] + b_o[4]);
            float cx, cy;
            if (dec_t == 0){
                cx = obs[7*1024 + bid*2]; cy = obs[7*1024 + bid*2 + 1];
                if (isnan(cx)) cx = 0.f;
                if (isnan(cy)) cy = 0.f;
                if (!mski[bid]){ cx = 0.f; cy = 0.f; }
            } else {
                cx = cur[bid*2]; cy = cur[bid*2 + 1];
            }
            if (mski[bid]){ cx += mu0; cy += mu1; }
            cur[bid*2] = cx; cur[bid*2 + 1] = cy;
            out[dec_t*1024 + bid*2]             = cx;
            out[dec_t*1024 + bid*2 + 1]         = cy;
            out[12288 + dec_t*1024 + bid*2]     = s0;
            out[12288 + dec_t*1024 + bid*2 + 1] = s1;
            out[24576 + dec_t*512 + bid]        = rh;
        }
    }
    if (t >= T_OBS + PRED) return;    // tail launch: head only

    // ---- U-GEMM ----
    const int mq = bid >> 5, cp = bid & 31;
    const int r0 = mq * 32;
    const int w = tid >> 6, lane = tid & 63;
    const int msub = w & 1, nq = w >> 1;
    const int lrow = lane & 15, lk = (lane >> 4) * 8;
    f32x4 acc[2][4] = {};
    #pragma unroll
    for (int ks = 0; ks < 4; ++ks){
        bf16x8 a = *(const bf16x8*)(hg + (r0 + msub*16 + lrow)*128 + ks*32 + lk);
        #pragma unroll
        for (int cell = 0; cell < 2; ++cell){
            #pragma unroll
            for (int ntl = 0; ntl < 4; ++ntl){
                const unsigned short* bp = wp_bf +
                    ((nq*4 + ntl)*16 + lrow)*8192 + (2*cp + cell)*128 + ks*32 + lk;
                acc[cell][ntl] = MFMA16(a, *(const bf16x8*)bp, acc[cell][ntl]);
            }
        }
    }
    const int crow = (lane >> 4) * 4, ccol = lane & 15;
    #pragma unroll
    for (int cell = 0; cell < 2; ++cell)
        #pragma unroll
        for (int ntl = 0; ntl < 4; ++ntl)
            #pragma unroll
            for (int r = 0; r < 4; ++r)
                ustage[msub*16 + crow + r][cell*128 + (nq*4 + ntl)*16 + ccol]
                    = f2bf(acc[cell][ntl][r]);
    __syncthreads();
    // non-temporal flush: U is a single-consumer stream -> don't dirty L2
    for (int e = tid; e < 1024; e += 256){
        int r = e >> 5, o = e & 31;
        u64x2 v = *(const u64x2*)&ustage[r][o*8];
        __builtin_nontemporal_store(v,
            (u64x2*)((char*)U + ((long long)(r0 + r)*64 + 2*cp)*256 + o*16));
    }
}

// ---------------- KG: [pos/cells/compact]|lst_pre + gather + soc/emb ----------
__global__ __launch_bounds__(256) void kg(
    const float* __restrict__ obs, const int* __restrict__ mski,
    const unsigned short* __restrict__ U,
    const float* __restrict__ W_e, const float* __restrict__ b_e,
    const float* __restrict__ b_p, const float* __restrict__ cur,
    const short* __restrict__ lst_pre, const int* __restrict__ nv_pre,
    unsigned short* __restrict__ xin, int t)
{
    __shared__ float2 pos[512];
    __shared__ short  cells_s[512];
    __shared__ short  lst[512];
    __shared__ int    nvS;
    __shared__ float  socp[8][128];
    const int bid = blockIdx.x, tid = threadIdx.x;

    float2 pi;
    int n;
    const int vi = mski[bid];

    if (t <= 8){
        const int to = (t < 8) ? t : 7;
        float px = obs[to*1024 + 2*bid], py = obs[to*1024 + 2*bid + 1];
        if (isnan(px)) px = 0.f;
        if (isnan(py)) py = 0.f;
        if (t == 8 && !vi){ px = 0.f; py = 0.f; }
        pi = make_float2(px, py);
        const short* lp = lst_pre + ((long long)t*512 + bid)*512;
        for (int e = tid; e < 512; e += 256) lst[e] = lp[e];
        n = nv_pre[t*512 + bid];
        __syncthreads();
    } else {
        for (int s = 0; s < 2; ++s){
            int j = tid + s*256;
            pos[j] = ((const float2*)cur)[j];
        }
        __syncthreads();
        pi = pos[bid];
        for (int s = 0; s < 2; ++s){
            int j = tid + s*256;
            int cc = -1;
            if (vi && j != bid && mski[j]){
                float rx = pos[j].x - pi.x, ry = pos[j].y - pi.y;
                if (fabsf(rx) < 32.f && fabsf(ry) < 32.f){
                    int col = (int)floorf((rx + 32.f) * 0.125f);
                    int row = (int)floorf((ry + 32.f) * 0.125f);
                    col = min(max(col, 0), 7); row = min(max(row, 0), 7);
                    cc = row*8 + col;
                }
            }
            cells_s[j] = (short)cc;
        }
        __syncthreads();
        if (tid < 64){
            int base = 0;
            for (int b = 0; b < 8; ++b){
                short cj = cells_s[b*64 + tid];
                bool val = cj >= 0;
                unsigned long long bal = __ballot(val);
                int pre = __popcll(bal & ((1ull << tid) - 1ull));
                if (val) lst[base + pre] = (short)((b*64 + tid) | ((int)cj << 9));
                base += __popcll(bal);
            }
            if (tid == 0) nvS = base;
        }
        __syncthreads();
        n = nvS;
    }

    // gather: 8 slots (tid>>5) x unroll 16 -> 128 rows in flight (NT loads)
    {
        const int slot = tid >> 5, lq = tid & 31;
        const unsigned long long* ub = (const unsigned long long*)U;
        float s0 = 0.f, s1 = 0.f, s2 = 0.f, s3 = 0.f;
        int b4 = 0;
        for (; b4 + 128 <= n; b4 += 128){
            unsigned long long v[16];
            #pragma unroll
            for (int u = 0; u < 16; ++u){
                int pk = lst[b4 + u*8 + slot];
                v[u] = __builtin_nontemporal_load(
                           ub + (pk & 511)*2048 + (pk >> 9)*32 + lq);
            }
            #pragma unroll
            for (int u = 0; u < 16; ++u){
                unsigned lo = (unsigned)v[u], hi = (unsigned)(v[u] >> 32);
                s0 += bf2lo(lo); s1 += bf2hi(lo);
                s2 += bf2lo(hi); s3 += bf2hi(hi);
            }
        }
        for (; b4 + 32 <= n; b4 += 32){
            unsigned long long v[4];
            #pragma unroll
            for (int u = 0; u < 4; ++u){
                int pk = lst[b4 + u*8 + slot];
                v[u] = __builtin_nontemporal_load(
                           ub + (pk & 511)*2048 + (pk >> 9)*32 + lq);
            }
            #pragma unroll
            for (int u = 0; u < 4; ++u){
                unsigned lo = (unsigned)v[u], hi = (unsigned)(v[u] >> 32);
                s0 += bf2lo(lo); s1 += bf2hi(lo);
                s2 += bf2lo(hi); s3 += bf2hi(hi);
            }
        }
        for (; b4 + 8 <= n; b4 += 8){
            int pk = lst[b4 + slot];
            unsigned long long v = __builtin_nontemporal_load(
                                       ub + (pk & 511)*2048 + (pk >> 9)*32 + lq);
            unsigned lo = (unsigned)v, hi = (unsigned)(v >> 32);
            s0 += bf2lo(lo); s1 += bf2hi(lo); s2 += bf2lo(hi); s3 += bf2hi(hi);
        }
        if (b4 + slot < n){
            int pk = lst[b4 + slot];
            unsigned long long v = __builtin_nontemporal_load(
                                       ub + (pk & 511)*2048 + (pk >> 9)*32 + lq);
            unsigned lo = (unsigned)v, hi = (unsigned)(v >> 32);
            s0 += bf2lo(lo); s1 += bf2hi(lo); s2 += bf2lo(hi); s3 += bf2hi(hi);
        }
        f32x4 sv = {s0, s1, s2, s3};
        *(f32x4*)&socp[slot][lq*4] = sv;
    }
    __syncthreads();
    if (tid < 128){
        float s = b_p[tid];
        #pragma unroll
        for (int p = 0; p < 8; ++p) s += socp[p][tid];
        if (!vi) s = 0.f;
        xin[bid*192 + 64 + tid] = f2bf(s);
    } else if (tid < 192){
        int u = tid - 128;
        float e = W_e[u*2]*pi.x + W_e[u*2 + 1]*pi.y + b_e[u];
        xin[bid*192 + u] = f2bf(fmaxf(e, 0.f));
    }
}

// ---------------- KL: batched LSTM, 256 blocks x 256 threads ------------------
// block (rt 0..31, uo 0..7): rows rt*16..+16, units uo*16..+16
// wave w: gh = w&1 (gates 2gh,2gh+1), p = w>>1 (K half). K-split via zpart.
__global__ __launch_bounds__(256) void kl(
    const unsigned short* __restrict__ xin, const unsigned short* __restrict__ hg_rd,
    const unsigned short* __restrict__ wz, const float* __restrict__ bz,
    float* __restrict__ cst, unsigned* __restrict__ hg_wr)
{
    __shared__ float zpart[2][4][16][16];   // 8 KB
    __shared__ float hst[16][17];           // 1.1 KB
    const int bid = blockIdx.x, tid = threadIdx.x;
    const int rt = bid >> 3, uo = bid & 7;
    const int r0 = rt * 16, u0 = uo * 16;
    const int w = tid >> 6, lane = tid & 63;
    const int gh = w & 1, p = w >> 1;
    const int lrow = lane & 15, lk = (lane >> 4) * 8;

    f32x4 acc[2] = {};
    #pragma unroll
    for (int kk = 0; kk < 5; ++kk){
        const int ks = p*5 + kk;
        const int row = r0 + lrow;
        bf16x8 a;
        if (ks < 6) a = *(const bf16x8*)(xin + row*192 + ks*32 + lk);
        else        a = *(const bf16x8*)(hg_rd + row*128 + (ks - 6)*32 + lk);
        #pragma unroll
        for (int gi = 0; gi < 2; ++gi){
            const int g = gh*2 + gi;
            bf16x8 b = *(const bf16x8*)(wz + (g*128 + u0 + lrow)*320 + ks*32 + lk);
            acc[gi] = MFMA16(a, b, acc[gi]);
        }
    }
    const int crow = (lane >> 4) * 4, ccol = lane & 15;
    #pragma unroll
    for (int gi = 0; gi < 2; ++gi)
        #pragma unroll
        for (int r = 0; r < 4; ++r)
            zpart[p][gh*2 + gi][crow + r][ccol] = acc[gi][r];
    __syncthreads();

    if (tid < 256){
        int row = tid >> 4, lu = tid & 15;
        int unit = u0 + lu;
        float zi = zpart[0][0][row][lu] + zpart[1][0][row][lu] + bz[      unit];
        float zf = zpart[0][1][row][lu] + zpart[1][1][row][lu] + bz[128 + unit];
        float zg = zpart[0][2][row][lu] + zpart[1][2][row][lu] + bz[256 + unit];
        float zo = zpart[0][3][row][lu] + zpart[1][3][row][lu] + bz[384 + unit];
        float ig = sigm_f(zi), fg = sigm_f(zf);
        float gv = tanh_f(zg), og = sigm_f(zo);
        int gi2 = (r0 + row)*128 + unit;
        float cn = fg * cst[gi2] + ig * gv;
        float hn = og * tanh_f(cn);
        cst[gi2] = cn;
        hst[row][lu] = hn;
    }
    __syncthreads();
    if (tid < 128){
        int row = tid >> 3, pp = tid & 7;
        hg_wr[(r0 + row)*64 + uo*8 + pp] = pack2(hst[row][2*pp], hst[row][2*pp + 1]);
    }
}

extern "C" void kernel_launch(void* const* d_in, const int* in_sizes, int n_in,
                              void* d_out, int out_size, void* d_ws, size_t ws_size,
                              hipStream_t stream)
{
    const float* obs  = (const float*)d_in[0];
    const unsigned char* mraw = (const unsigned char*)d_in[1];
    const float* W_e  = (const float*)d_in[2];
    const float* b_e  = (const float*)d_in[3];
    const float* W_p  = (const float*)d_in[4];
    const float* b_p  = (const float*)d_in[5];
    const float* W_ih = (const float*)d_in[6];
    const float* W_hh = (const float*)d_in[7];
    const float* b_ih = (const float*)d_in[8];
    const float* b_hh = (const float*)d_in[9];
    const float* W_o  = (const float*)d_in[10];
    const float* b_o  = (const float*)d_in[11];
    float* out = (float*)d_out;

    char* ws = (char*)d_ws;
    unsigned short* wp_bf = (unsigned short*)(ws + WP_OFF);
    unsigned short* wz_bf = (unsigned short*)(ws + WZ_OFF);
    float* bz   = (float*)(ws + BZ_OFF);
    int*   mski = (int*)  (ws + MASK_OFF);
    float* cur  = (float*)(ws + CUR_OFF);
    unsigned short* hg[2] = { (unsigned short*)(ws + HG0_OFF),
                              (unsigned short*)(ws + HG1_OFF) };
    float* cst  = (float*)(ws + CST_OFF);
    unsigned short* xin = (unsigned short*)(ws + XIN_OFF);
    unsigned short* U   = (unsigned short*)(ws + U_OFF);
    short* lst_pre = (short*)(ws + LSTP_OFF);
    int*   nv_pre  = (int*)  (ws + NVP_OFF);

    prep<<<512, 256, 0, stream>>>(obs, W_p, W_ih, W_hh, b_ih, b_hh, mraw,
                                  W_e, b_e, b_p,
                                  wp_bf, wz_bf, bz, mski, (unsigned*)hg[1], cst,
                                  lst_pre, nv_pre, xin);

    for (int t = 0; t < T_OBS + PRED; ++t){
        // kl(t): reads h(t-1) from hg[(t+1)&1], writes h(t) to hg[t&1]
        if (t > 0){
            ku<<<512, 256, 0, stream>>>(hg[(t - 1) & 1], wp_bf, obs, W_o, b_o,
                                        mski, cur, out, U, t);
            kg<<<512, 256, 0, stream>>>(obs, mski, U, W_e, b_e, b_p, cur,
                                        lst_pre, nv_pre, xin, t);
        }
        kl<<<256, 256, 0, stream>>>(xin, hg[(t + 1) & 1], wz_bf, bz, cst,
                                    (unsigned*)hg[t & 1]);
    }
    // tail: decoder head d = 11 from h(19) (in hg[19&1] = hg[1])
    ku<<<512, 256, 0, stream>>>(hg[1], wp_bf, obs, W_o, b_o, mski,
                                cur, out, U, T_OBS + PRED);
}